// Round 2
// baseline (498.627 us; speedup 1.0000x reference)
//
#include <hip/hip_runtime.h>

typedef __attribute__((ext_vector_type(8))) __bf16 bf16x8;
typedef __attribute__((ext_vector_type(4))) float f32x4;

#define NB   4
#define NS   2048
#define NDIN 1024
#define NH   16
#define ND   64
#define NHD  1024
#define NM   (NB * NS)  // 8192

__device__ __forceinline__ float bf2f(unsigned short u) {
    unsigned int x = ((unsigned int)u) << 16;
    return __builtin_bit_cast(float, x);
}
__device__ __forceinline__ unsigned short f2bf(float f) {
    unsigned int u = __builtin_bit_cast(unsigned int, f);
    u += 0x7fff + ((u >> 16) & 1);  // RNE
    return (unsigned short)(u >> 16);
}

// ---------------- X: fp32 -> bf16, 8 elems/thread ----------------
__global__ __launch_bounds__(256) void cvt_x(const float* __restrict__ src,
                                             unsigned short* __restrict__ dst) {
    int i = blockIdx.x * 256 + threadIdx.x;  // one 8-elem chunk per thread
    float4 a = ((const float4*)src)[i * 2];
    float4 b = ((const float4*)src)[i * 2 + 1];
    union { uint4 u; unsigned short s[8]; } o;
    o.s[0] = f2bf(a.x); o.s[1] = f2bf(a.y); o.s[2] = f2bf(a.z); o.s[3] = f2bf(a.w);
    o.s[4] = f2bf(b.x); o.s[5] = f2bf(b.y); o.s[6] = f2bf(b.z); o.s[7] = f2bf(b.w);
    *(uint4*)(dst + (size_t)i * 8) = o.u;
}

// ------------- weight transpose+convert: fp32 src[K][N] -> bf16 dst[N][K] -------------
__global__ void transpose_cvt(const float* __restrict__ src,
                              unsigned short* __restrict__ dst, int K, int N) {
    __shared__ unsigned short t[32][33];
    int k0 = blockIdx.x * 32, n0 = blockIdx.y * 32;
    int tx = threadIdx.x, ty = threadIdx.y;  // block (32,8)
#pragma unroll
    for (int i = 0; i < 32; i += 8)
        t[ty + i][tx] = f2bf(src[(size_t)(k0 + ty + i) * N + (n0 + tx)]);
    __syncthreads();
#pragma unroll
    for (int i = 0; i < 32; i += 8)
        dst[(size_t)(n0 + ty + i) * K + (k0 + tx)] = t[tx][ty + i];
}

// ---------------- fused QKV projection: Xb[8192][1024] @ {wq,wk,wv} ----------------
// Wt rows 0..1023 = wq^T, 1024..2047 = wk^T, 2048..3071 = wv^T (bf16).
// Output scattered into Q/K/V as [B,H,S,D] bf16; bias fp32.
__global__ __launch_bounds__(256) void gemm_qkv(
    const unsigned short* __restrict__ X, const unsigned short* __restrict__ Wt,
    const float* __restrict__ bq, const float* __restrict__ bk,
    const float* __restrict__ bv,
    unsigned short* __restrict__ Q, unsigned short* __restrict__ K,
    unsigned short* __restrict__ V) {
    __shared__ unsigned short Al[128][40];  // 128 rows x 32 k (pad->40)
    __shared__ unsigned short Bl[128][40];
    int mb = blockIdx.x * 128;
    int nb = blockIdx.y * 128;
    int tid = threadIdx.x;
    int wid = tid >> 6, lane = tid & 63, quad = lane >> 4, l16 = lane & 15;
    int wm = (wid & 1) * 64, wn = (wid >> 1) * 64;

    f32x4 acc[4][4];
#pragma unroll
    for (int i = 0; i < 4; i++)
#pragma unroll
        for (int j = 0; j < 4; j++) acc[i][j] = (f32x4){0.f, 0.f, 0.f, 0.f};

    for (int k0 = 0; k0 < NDIN; k0 += 32) {
#pragma unroll
        for (int i = 0; i < 2; i++) {
            int c = tid + 256 * i;                 // 0..511 chunks of 16B
            int row = c >> 2, col = (c & 3) * 8;   // 4 chunks per 32-elem row
            uint4 a = *(const uint4*)(X + (size_t)(mb + row) * NDIN + k0 + col);
            *(uint4*)(&Al[row][col]) = a;
            uint4 b = *(const uint4*)(Wt + (size_t)(nb + row) * NDIN + k0 + col);
            *(uint4*)(&Bl[row][col]) = b;
        }
        __syncthreads();
        bf16x8 af[4], bfr[4];
#pragma unroll
        for (int i = 0; i < 4; i++)
            af[i] = *(const bf16x8*)(&Al[wm + i * 16 + l16][quad * 8]);
#pragma unroll
        for (int j = 0; j < 4; j++)
            bfr[j] = *(const bf16x8*)(&Bl[wn + j * 16 + l16][quad * 8]);
#pragma unroll
        for (int i = 0; i < 4; i++)
#pragma unroll
            for (int j = 0; j < 4; j++)
                acc[i][j] = __builtin_amdgcn_mfma_f32_16x16x32_bf16(af[i], bfr[j], acc[i][j], 0, 0, 0);
        __syncthreads();
    }

#pragma unroll
    for (int i = 0; i < 4; i++) {
#pragma unroll
        for (int j = 0; j < 4; j++) {
            int n = nb + wn + j * 16 + l16;  // global column in [0,3072)
            int wsel = n >> 10;
            int cc = n & 1023;
            const float* bias = (wsel == 0) ? bq : (wsel == 1) ? bk : bv;
            unsigned short* dstp = (wsel == 0) ? Q : (wsel == 1) ? K : V;
            float bias_v = bias[cc];
            int h = cc >> 6, d = cc & 63;
#pragma unroll
            for (int r = 0; r < 4; r++) {
                int m = mb + wm + i * 16 + quad * 4 + r;  // row in [0,8192)
                int b = m >> 11, s = m & 2047;
                dstp[((size_t)((b * NH + h) * NS + s)) * ND + d] = f2bf(acc[i][j][r] + bias_v);
            }
        }
    }
}

// ---------------- flash attention over [B,H,S,D] ----------------
// block = 4 waves; block handles (bh, 64 q rows); wave handles 16 q rows.
__global__ __launch_bounds__(256) void attn(
    const unsigned short* __restrict__ Q, const unsigned short* __restrict__ K,
    const unsigned short* __restrict__ V, unsigned short* __restrict__ Obuf) {
    __shared__ unsigned short Kl[64][72];       // [key][d], pad 64->72
    __shared__ unsigned short Vt[64][72];       // [d][key], pad 64->72
    __shared__ unsigned short Pl[4][16][72];    // per-wave P [q][key]
    int qt = blockIdx.x;  // 0..31
    int bh = blockIdx.y;  // 0..63
    size_t base = (size_t)bh * NS * ND;
    int tid = threadIdx.x, wid = tid >> 6, lane = tid & 63;
    int quad = lane >> 4, l16 = lane & 15;
    int q0 = qt * 64 + wid * 16;

    // Q fragments (A-layout), pre-scaled by 1/sqrt(D)=0.125 (exact in bf16)
    bf16x8 qa[2];
#pragma unroll
    for (int f = 0; f < 2; f++) {
        union { uint4 u; unsigned short s[8]; } in_, out_;
        in_.u = *(const uint4*)(Q + base + (size_t)(q0 + l16) * ND + f * 32 + quad * 8);
#pragma unroll
        for (int j = 0; j < 8; j++) out_.s[j] = f2bf(bf2f(in_.s[j]) * 0.125f);
        qa[f] = __builtin_bit_cast(bf16x8, out_.u);
    }

    float mrow[4], lrow[4];
    f32x4 o[4];
#pragma unroll
    for (int r = 0; r < 4; r++) { mrow[r] = -1e30f; lrow[r] = 0.f; }
#pragma unroll
    for (int t = 0; t < 4; t++) o[t] = (f32x4){0.f, 0.f, 0.f, 0.f};

    for (int kc = 0; kc < NS; kc += 64) {
        // stage K chunk [64][64] and V chunk transposed [d][key]
#pragma unroll
        for (int i = 0; i < 2; i++) {
            int c = tid + 256 * i;
            int row = c >> 3, col = (c & 7) * 8;
            uint4 kd = *(const uint4*)(K + base + (size_t)(kc + row) * ND + col);
            *(uint4*)(&Kl[row][col]) = kd;
            union { uint4 u; unsigned short s[8]; } vv;
            vv.u = *(const uint4*)(V + base + (size_t)(kc + row) * ND + col);
#pragma unroll
            for (int j = 0; j < 8; j++) Vt[col + j][row] = vv.s[j];
        }
        __syncthreads();

        // S = Q K^T  (C-layout: key=l16 within subtile, qrow=quad*4+r)
        f32x4 sc[4];
#pragma unroll
        for (int sub = 0; sub < 4; sub++) {
            bf16x8 kb0 = *(const bf16x8*)(&Kl[sub * 16 + l16][quad * 8]);
            bf16x8 kb1 = *(const bf16x8*)(&Kl[sub * 16 + l16][32 + quad * 8]);
            f32x4 c = (f32x4){0.f, 0.f, 0.f, 0.f};
            c = __builtin_amdgcn_mfma_f32_16x16x32_bf16(qa[0], kb0, c, 0, 0, 0);
            c = __builtin_amdgcn_mfma_f32_16x16x32_bf16(qa[1], kb1, c, 0, 0, 0);
            sc[sub] = c;
        }

        // online softmax (row stats via 16-lane shuffle reduce)
#pragma unroll
        for (int r = 0; r < 4; r++) {
            float mx = fmaxf(fmaxf(sc[0][r], sc[1][r]), fmaxf(sc[2][r], sc[3][r]));
#pragma unroll
            for (int s = 8; s >= 1; s >>= 1) mx = fmaxf(mx, __shfl_xor(mx, s, 64));
            float mn = fmaxf(mrow[r], mx);
            float alpha = __expf(mrow[r] - mn);
            mrow[r] = mn;
            float sum = 0.f;
#pragma unroll
            for (int sub = 0; sub < 4; sub++) {
                float p = __expf(sc[sub][r] - mn);
                sc[sub][r] = p;
                sum += p;
            }
#pragma unroll
            for (int s = 8; s >= 1; s >>= 1) sum += __shfl_xor(sum, s, 64);
            lrow[r] = lrow[r] * alpha + sum;
#pragma unroll
            for (int t = 0; t < 4; t++) o[t][r] *= alpha;
        }

        // P: C-layout -> LDS -> A-layout
#pragma unroll
        for (int sub = 0; sub < 4; sub++)
#pragma unroll
            for (int r = 0; r < 4; r++)
                Pl[wid][quad * 4 + r][sub * 16 + l16] = f2bf(sc[sub][r]);
        __syncthreads();

        bf16x8 pa0 = *(const bf16x8*)(&Pl[wid][l16][quad * 8]);
        bf16x8 pa1 = *(const bf16x8*)(&Pl[wid][l16][32 + quad * 8]);
#pragma unroll
        for (int t = 0; t < 4; t++) {
            bf16x8 vb0 = *(const bf16x8*)(&Vt[t * 16 + l16][quad * 8]);
            bf16x8 vb1 = *(const bf16x8*)(&Vt[t * 16 + l16][32 + quad * 8]);
            o[t] = __builtin_amdgcn_mfma_f32_16x16x32_bf16(pa0, vb0, o[t], 0, 0, 0);
            o[t] = __builtin_amdgcn_mfma_f32_16x16x32_bf16(pa1, vb1, o[t], 0, 0, 0);
        }
        __syncthreads();  // protect Kl/Vt before next stage
    }

    int b = bh >> 4, h = bh & 15;
#pragma unroll
    for (int t = 0; t < 4; t++)
#pragma unroll
        for (int r = 0; r < 4; r++) {
            int srow = q0 + quad * 4 + r;
            float val = o[t][r] / lrow[r];
            Obuf[(size_t)(b * NS + srow) * NHD + h * ND + t * 16 + l16] = f2bf(val);
        }
}

// ---------------- output projection: Obuf[8192][1024] @ wo[1024][64] + bo -> fp32 ----------------
__global__ __launch_bounds__(64) void out_proj(
    const unsigned short* __restrict__ Obuf, const unsigned short* __restrict__ WoT,
    const float* __restrict__ bo, float* __restrict__ Out) {
    int m0 = blockIdx.x * 16;  // grid 512
    int lane = threadIdx.x, quad = lane >> 4, l16 = lane & 15;
    f32x4 acc[4];
#pragma unroll
    for (int t = 0; t < 4; t++) acc[t] = (f32x4){0.f, 0.f, 0.f, 0.f};
    for (int k0 = 0; k0 < NHD; k0 += 32) {
        bf16x8 a = *(const bf16x8*)(Obuf + (size_t)(m0 + l16) * NHD + k0 + quad * 8);
#pragma unroll
        for (int t = 0; t < 4; t++) {
            bf16x8 b = *(const bf16x8*)(WoT + (size_t)(t * 16 + l16) * NHD + k0 + quad * 8);
            acc[t] = __builtin_amdgcn_mfma_f32_16x16x32_bf16(a, b, acc[t], 0, 0, 0);
        }
    }
#pragma unroll
    for (int t = 0; t < 4; t++) {
        int n = t * 16 + l16;
        float bb = bo[n];
#pragma unroll
        for (int r = 0; r < 4; r++) {
            int m = m0 + quad * 4 + r;
            Out[(size_t)m * ND + n] = acc[t][r] + bb;
        }
    }
}

extern "C" void kernel_launch(void* const* d_in, const int* in_sizes, int n_in,
                              void* d_out, int out_size, void* d_ws, size_t ws_size,
                              hipStream_t stream) {
    const float* X  = (const float*)d_in[0];
    const float* wq = (const float*)d_in[1];
    const float* bq = (const float*)d_in[2];
    const float* wk = (const float*)d_in[3];
    const float* bk = (const float*)d_in[4];
    const float* wv = (const float*)d_in[5];
    const float* bv = (const float*)d_in[6];
    const float* wo = (const float*)d_in[7];
    const float* bo = (const float*)d_in[8];
    float* Out = (float*)d_out;

    char* w = (char*)d_ws;
    unsigned short* Wt  = (unsigned short*)w; w += (size_t)3072 * 1024 * 2;
    unsigned short* WoT = (unsigned short*)w; w += (size_t)64 * 1024 * 2;
    unsigned short* Xb  = (unsigned short*)w; w += (size_t)NM * NDIN * 2;
    unsigned short* Qb  = (unsigned short*)w; w += (size_t)NM * NHD * 2;
    unsigned short* Kb  = (unsigned short*)w; w += (size_t)NM * NHD * 2;
    unsigned short* Vb  = (unsigned short*)w; w += (size_t)NM * NHD * 2;
    unsigned short* Ob  = (unsigned short*)w; w += (size_t)NM * NHD * 2;

    cvt_x<<<NM * NDIN / (256 * 8), 256, 0, stream>>>(X, Xb);

    dim3 tb(32, 8);
    transpose_cvt<<<dim3(32, 32), tb, 0, stream>>>(wq, Wt, 1024, 1024);
    transpose_cvt<<<dim3(32, 32), tb, 0, stream>>>(wk, Wt + 1024 * 1024, 1024, 1024);
    transpose_cvt<<<dim3(32, 32), tb, 0, stream>>>(wv, Wt + 2 * 1024 * 1024, 1024, 1024);
    transpose_cvt<<<dim3(32, 2),  tb, 0, stream>>>(wo, WoT, 1024, 64);

    gemm_qkv<<<dim3(64, 24), 256, 0, stream>>>(Xb, Wt, bq, bk, bv, Qb, Kb, Vb);
    attn<<<dim3(32, 64), 256, 0, stream>>>(Qb, Kb, Vb, Ob);
    out_proj<<<512, 64, 0, stream>>>(Ob, WoT, bo, Out);
}

// Round 3
// 423.529 us; speedup vs baseline: 1.1773x; 1.1773x over previous
//
#include <hip/hip_runtime.h>

typedef __attribute__((ext_vector_type(8))) __bf16 bf16x8;
typedef __attribute__((ext_vector_type(4))) float f32x4;

#define NB   4
#define NS   2048
#define NDIN 1024
#define NH   16
#define ND   64
#define NHD  1024
#define NM   (NB * NS)  // 8192

__device__ __forceinline__ float bf2f(unsigned short u) {
    unsigned int x = ((unsigned int)u) << 16;
    return __builtin_bit_cast(float, x);
}
__device__ __forceinline__ unsigned short f2bf(float f) {
    unsigned int u = __builtin_bit_cast(unsigned int, f);
    u += 0x7fff + ((u >> 16) & 1);  // RNE
    return (unsigned short)(u >> 16);
}

// ---------------- X: fp32 -> bf16, 8 elems/thread ----------------
__global__ __launch_bounds__(256) void cvt_x(const float* __restrict__ src,
                                             unsigned short* __restrict__ dst) {
    int i = blockIdx.x * 256 + threadIdx.x;
    float4 a = ((const float4*)src)[i * 2];
    float4 b = ((const float4*)src)[i * 2 + 1];
    union { uint4 u; unsigned short s[8]; } o;
    o.s[0] = f2bf(a.x); o.s[1] = f2bf(a.y); o.s[2] = f2bf(a.z); o.s[3] = f2bf(a.w);
    o.s[4] = f2bf(b.x); o.s[5] = f2bf(b.y); o.s[6] = f2bf(b.z); o.s[7] = f2bf(b.w);
    *(uint4*)(dst + (size_t)i * 8) = o.u;
}

// ------------- weight transpose+convert: fp32 src[K][N] -> bf16 dst[N][K] -------------
__global__ void transpose_cvt(const float* __restrict__ src,
                              unsigned short* __restrict__ dst, int K, int N) {
    __shared__ unsigned short t[32][33];
    int k0 = blockIdx.x * 32, n0 = blockIdx.y * 32;
    int tx = threadIdx.x, ty = threadIdx.y;  // block (32,8)
#pragma unroll
    for (int i = 0; i < 32; i += 8)
        t[ty + i][tx] = f2bf(src[(size_t)(k0 + ty + i) * N + (n0 + tx)]);
    __syncthreads();
#pragma unroll
    for (int i = 0; i < 32; i += 8)
        dst[(size_t)(n0 + ty + i) * K + (k0 + tx)] = t[tx][ty + i];
}

// ---------------- fused QKV projection: Xb[8192][1024] @ {wq,wk,wv} ----------------
__global__ __launch_bounds__(256) void gemm_qkv(
    const unsigned short* __restrict__ X, const unsigned short* __restrict__ Wt,
    const float* __restrict__ bq, const float* __restrict__ bk,
    const float* __restrict__ bv,
    unsigned short* __restrict__ Q, unsigned short* __restrict__ K,
    unsigned short* __restrict__ V) {
    __shared__ unsigned short Al[128][40];
    __shared__ unsigned short Bl[128][40];
    int mb = blockIdx.x * 128;
    int nb = blockIdx.y * 128;
    int tid = threadIdx.x;
    int wid = tid >> 6, lane = tid & 63, quad = lane >> 4, l16 = lane & 15;
    int wm = (wid & 1) * 64, wn = (wid >> 1) * 64;

    f32x4 acc[4][4];
#pragma unroll
    for (int i = 0; i < 4; i++)
#pragma unroll
        for (int j = 0; j < 4; j++) acc[i][j] = (f32x4){0.f, 0.f, 0.f, 0.f};

    for (int k0 = 0; k0 < NDIN; k0 += 32) {
#pragma unroll
        for (int i = 0; i < 2; i++) {
            int c = tid + 256 * i;
            int row = c >> 2, col = (c & 3) * 8;
            uint4 a = *(const uint4*)(X + (size_t)(mb + row) * NDIN + k0 + col);
            *(uint4*)(&Al[row][col]) = a;
            uint4 b = *(const uint4*)(Wt + (size_t)(nb + row) * NDIN + k0 + col);
            *(uint4*)(&Bl[row][col]) = b;
        }
        __syncthreads();
        bf16x8 af[4], bfr[4];
#pragma unroll
        for (int i = 0; i < 4; i++)
            af[i] = *(const bf16x8*)(&Al[wm + i * 16 + l16][quad * 8]);
#pragma unroll
        for (int j = 0; j < 4; j++)
            bfr[j] = *(const bf16x8*)(&Bl[wn + j * 16 + l16][quad * 8]);
#pragma unroll
        for (int i = 0; i < 4; i++)
#pragma unroll
            for (int j = 0; j < 4; j++)
                acc[i][j] = __builtin_amdgcn_mfma_f32_16x16x32_bf16(af[i], bfr[j], acc[i][j], 0, 0, 0);
        __syncthreads();
    }

#pragma unroll
    for (int i = 0; i < 4; i++) {
#pragma unroll
        for (int j = 0; j < 4; j++) {
            int n = nb + wn + j * 16 + l16;
            int wsel = n >> 10;
            int cc = n & 1023;
            const float* bias = (wsel == 0) ? bq : (wsel == 1) ? bk : bv;
            unsigned short* dstp = (wsel == 0) ? Q : (wsel == 1) ? K : V;
            float bias_v = bias[cc];
            int h = cc >> 6, d = cc & 63;
#pragma unroll
            for (int r = 0; r < 4; r++) {
                int m = mb + wm + i * 16 + quad * 4 + r;
                int b = m >> 11, s = m & 2047;
                dstp[((size_t)((b * NH + h) * NS + s)) * ND + d] = f2bf(acc[i][j][r] + bias_v);
            }
        }
    }
}

// ---------------- flash attention over [B,H,S,D] ----------------
// block = 4 waves, 128 q rows; wave handles 32 q rows (2 subtiles of 16).
__global__ __launch_bounds__(256) void attn(
    const unsigned short* __restrict__ Q, const unsigned short* __restrict__ K,
    const unsigned short* __restrict__ V, unsigned short* __restrict__ Obuf) {
    __shared__ unsigned short Kl[64][72];    // [key][d]
    __shared__ unsigned short Vt[64][72];    // [d][key]  (conflict-free staging)
    __shared__ unsigned short Pl[4][32][72]; // per-wave P, xor-swizzled columns
    int qt = blockIdx.x;  // 0..15
    int bh = blockIdx.y;  // 0..63
    size_t base = (size_t)bh * NS * ND;
    int tid = threadIdx.x, wid = tid >> 6, lane = tid & 63;
    int quad = lane >> 4, l16 = lane & 15;
    int q0 = qt * 128 + wid * 32;

    // Q fragments (A-layout), pre-scaled by 1/sqrt(D)=0.125 (exact in bf16)
    bf16x8 qa[2][2];
#pragma unroll
    for (int s = 0; s < 2; s++)
#pragma unroll
        for (int f = 0; f < 2; f++) {
            union { uint4 u; unsigned short sv[8]; } in_, out_;
            in_.u = *(const uint4*)(Q + base + (size_t)(q0 + s * 16 + l16) * ND + f * 32 + quad * 8);
#pragma unroll
            for (int j = 0; j < 8; j++) out_.sv[j] = f2bf(bf2f(in_.sv[j]) * 0.125f);
            qa[s][f] = __builtin_bit_cast(bf16x8, out_.u);
        }

    float mrow[2][4], lrow[2][4];
    f32x4 o[2][4];
#pragma unroll
    for (int s = 0; s < 2; s++)
#pragma unroll
        for (int r = 0; r < 4; r++) { mrow[s][r] = -1e30f; lrow[s][r] = 0.f; }
#pragma unroll
    for (int s = 0; s < 2; s++)
#pragma unroll
        for (int t = 0; t < 4; t++) o[s][t] = (f32x4){0.f, 0.f, 0.f, 0.f};

    for (int kc = 0; kc < NS; kc += 64) {
        // stage K [key][d] (coalesced, b128 LDS writes)
        // stage V transposed: lane = key -> bank = all 32, 2-way (free)
#pragma unroll
        for (int i = 0; i < 2; i++) {
            int c = tid + 256 * i;
            int row = c >> 3, col = (c & 7) * 8;
            uint4 kd = *(const uint4*)(K + base + (size_t)(kc + row) * ND + col);
            *(uint4*)(&Kl[row][col]) = kd;
            int key = c & 63, d0 = (c >> 6) * 8;
            union { uint4 u; unsigned short sv[8]; } vv;
            vv.u = *(const uint4*)(V + base + (size_t)(kc + key) * ND + d0);
#pragma unroll
            for (int j = 0; j < 8; j++) Vt[d0 + j][key] = vv.sv[j];
        }
        __syncthreads();

        // S = Q K^T
        f32x4 sc[2][4];
#pragma unroll
        for (int sub = 0; sub < 4; sub++) {
            bf16x8 kb0 = *(const bf16x8*)(&Kl[sub * 16 + l16][quad * 8]);
            bf16x8 kb1 = *(const bf16x8*)(&Kl[sub * 16 + l16][32 + quad * 8]);
#pragma unroll
            for (int s = 0; s < 2; s++) {
                f32x4 c = (f32x4){0.f, 0.f, 0.f, 0.f};
                c = __builtin_amdgcn_mfma_f32_16x16x32_bf16(qa[s][0], kb0, c, 0, 0, 0);
                c = __builtin_amdgcn_mfma_f32_16x16x32_bf16(qa[s][1], kb1, c, 0, 0, 0);
                sc[s][sub] = c;
            }
        }

        // online softmax
#pragma unroll
        for (int s = 0; s < 2; s++)
#pragma unroll
            for (int r = 0; r < 4; r++) {
                float mx = fmaxf(fmaxf(sc[s][0][r], sc[s][1][r]), fmaxf(sc[s][2][r], sc[s][3][r]));
#pragma unroll
                for (int sh = 8; sh >= 1; sh >>= 1) mx = fmaxf(mx, __shfl_xor(mx, sh, 64));
                float mn = fmaxf(mrow[s][r], mx);
                float alpha = __expf(mrow[s][r] - mn);
                mrow[s][r] = mn;
                float sum = 0.f;
#pragma unroll
                for (int sub = 0; sub < 4; sub++) {
                    float p = __expf(sc[s][sub][r] - mn);
                    sc[s][sub][r] = p;
                    sum += p;
                }
#pragma unroll
                for (int sh = 8; sh >= 1; sh >>= 1) sum += __shfl_xor(sum, sh, 64);
                lrow[s][r] = lrow[s][r] * alpha + sum;
#pragma unroll
                for (int t = 0; t < 4; t++) o[s][t][r] *= alpha;
            }

        // P: C-layout -> LDS (xor-swizzled col: phys = (keygrp ^ ((row>>2)&3))*16 + key15)
#pragma unroll
        for (int s = 0; s < 2; s++)
#pragma unroll
            for (int sub = 0; sub < 4; sub++)
#pragma unroll
                for (int r = 0; r < 4; r++)
                    Pl[wid][s * 16 + quad * 4 + r][((sub ^ quad) << 4) + l16] = f2bf(sc[s][sub][r]);
        __syncthreads();

        // P A-frags (deswizzle: row = s*16+l16 -> g = l16>>2)
        bf16x8 pa[2][2];
#pragma unroll
        for (int s = 0; s < 2; s++)
#pragma unroll
            for (int f = 0; f < 2; f++) {
                int cg = (f * 2 + (quad >> 1)) ^ (l16 >> 2);
                pa[s][f] = *(const bf16x8*)(&Pl[wid][s * 16 + l16][(cg << 4) + (quad & 1) * 8]);
            }
#pragma unroll
        for (int t = 0; t < 4; t++) {
            bf16x8 vb0 = *(const bf16x8*)(&Vt[t * 16 + l16][quad * 8]);
            bf16x8 vb1 = *(const bf16x8*)(&Vt[t * 16 + l16][32 + quad * 8]);
#pragma unroll
            for (int s = 0; s < 2; s++) {
                o[s][t] = __builtin_amdgcn_mfma_f32_16x16x32_bf16(pa[s][0], vb0, o[s][t], 0, 0, 0);
                o[s][t] = __builtin_amdgcn_mfma_f32_16x16x32_bf16(pa[s][1], vb1, o[s][t], 0, 0, 0);
            }
        }
        __syncthreads();  // protect Kl/Vt before next stage
    }

    int b = bh >> 4, h = bh & 15;
#pragma unroll
    for (int s = 0; s < 2; s++)
#pragma unroll
        for (int t = 0; t < 4; t++)
#pragma unroll
            for (int r = 0; r < 4; r++) {
                int srow = q0 + s * 16 + quad * 4 + r;
                float val = o[s][t][r] / lrow[s][r];
                Obuf[(size_t)(b * NS + srow) * NHD + h * ND + t * 16 + l16] = f2bf(val);
            }
}

// ---------------- output projection: Obuf[8192][1024] @ wo[1024][64] + bo -> fp32 ----------------
__global__ __launch_bounds__(64) void out_proj(
    const unsigned short* __restrict__ Obuf, const unsigned short* __restrict__ WoT,
    const float* __restrict__ bo, float* __restrict__ Out) {
    int m0 = blockIdx.x * 16;
    int lane = threadIdx.x, quad = lane >> 4, l16 = lane & 15;
    f32x4 acc[4];
#pragma unroll
    for (int t = 0; t < 4; t++) acc[t] = (f32x4){0.f, 0.f, 0.f, 0.f};
    for (int k0 = 0; k0 < NHD; k0 += 32) {
        bf16x8 a = *(const bf16x8*)(Obuf + (size_t)(m0 + l16) * NHD + k0 + quad * 8);
#pragma unroll
        for (int t = 0; t < 4; t++) {
            bf16x8 b = *(const bf16x8*)(WoT + (size_t)(t * 16 + l16) * NHD + k0 + quad * 8);
            acc[t] = __builtin_amdgcn_mfma_f32_16x16x32_bf16(a, b, acc[t], 0, 0, 0);
        }
    }
#pragma unroll
    for (int t = 0; t < 4; t++) {
        int n = t * 16 + l16;
        float bb = bo[n];
#pragma unroll
        for (int r = 0; r < 4; r++) {
            int m = m0 + quad * 4 + r;
            Out[(size_t)m * ND + n] = acc[t][r] + bb;
        }
    }
}

extern "C" void kernel_launch(void* const* d_in, const int* in_sizes, int n_in,
                              void* d_out, int out_size, void* d_ws, size_t ws_size,
                              hipStream_t stream) {
    const float* X  = (const float*)d_in[0];
    const float* wq = (const float*)d_in[1];
    const float* bq = (const float*)d_in[2];
    const float* wk = (const float*)d_in[3];
    const float* bk = (const float*)d_in[4];
    const float* wv = (const float*)d_in[5];
    const float* bv = (const float*)d_in[6];
    const float* wo = (const float*)d_in[7];
    const float* bo = (const float*)d_in[8];
    float* Out = (float*)d_out;

    char* w = (char*)d_ws;
    unsigned short* Wt  = (unsigned short*)w; w += (size_t)3072 * 1024 * 2;
    unsigned short* WoT = (unsigned short*)w; w += (size_t)64 * 1024 * 2;
    unsigned short* Xb  = (unsigned short*)w; w += (size_t)NM * NDIN * 2;
    unsigned short* Qb  = (unsigned short*)w; w += (size_t)NM * NHD * 2;
    unsigned short* Kb  = (unsigned short*)w; w += (size_t)NM * NHD * 2;
    unsigned short* Vb  = (unsigned short*)w; w += (size_t)NM * NHD * 2;
    unsigned short* Ob  = (unsigned short*)w; w += (size_t)NM * NHD * 2;

    cvt_x<<<NM * NDIN / (256 * 8), 256, 0, stream>>>(X, Xb);

    dim3 tb(32, 8);
    transpose_cvt<<<dim3(32, 32), tb, 0, stream>>>(wq, Wt, 1024, 1024);
    transpose_cvt<<<dim3(32, 32), tb, 0, stream>>>(wk, Wt + 1024 * 1024, 1024, 1024);
    transpose_cvt<<<dim3(32, 32), tb, 0, stream>>>(wv, Wt + 2 * 1024 * 1024, 1024, 1024);
    transpose_cvt<<<dim3(32, 2),  tb, 0, stream>>>(wo, WoT, 1024, 64);

    gemm_qkv<<<dim3(64, 24), 256, 0, stream>>>(Xb, Wt, bq, bk, bv, Qb, Kb, Vb);
    attn<<<dim3(16, 64), 256, 0, stream>>>(Qb, Kb, Vb, Ob);
    out_proj<<<512, 64, 0, stream>>>(Ob, WoT, bo, Out);
}